// Round 1
// baseline (1873.456 us; speedup 1.0000x reference)
//
#include <hip/hip_runtime.h>
#include <hip/hip_bf16.h>

#define BS 2
#define QLEN 2048
#define DIM 2048
#define H 16
#define DH 128
#define MTOT (BS*QLEN)

typedef __hip_bfloat16 bf16;
using f32x4 = __attribute__((ext_vector_type(4))) float;
using s16x8 = __attribute__((ext_vector_type(8))) short;

__device__ inline void gload_lds16(const bf16* g, bf16* l) {
    __builtin_amdgcn_global_load_lds(
        (const __attribute__((address_space(1))) void*)g,
        (__attribute__((address_space(3))) void*)l,
        16, 0, 0);
}

// ---------------- fp32 -> bf16 cast (float4 in, bf162 pairs out) ----------------
__global__ __launch_bounds__(256) void cast_kernel(const float* __restrict__ in,
                                                   bf16* __restrict__ out, int n4) {
    int i = blockIdx.x * 256 + threadIdx.x;
    if (i < n4) {
        float4 v = ((const float4*)in)[i];
        __hip_bfloat162 p0 = __float22bfloat162_rn(make_float2(v.x, v.y));
        __hip_bfloat162 p1 = __float22bfloat162_rn(make_float2(v.z, v.w));
        ((__hip_bfloat162*)out)[2*i]   = p0;
        ((__hip_bfloat162*)out)[2*i+1] = p1;
    }
}

// ---------------- GEMM: C = A(MxK) * B(NxK)^T + bias, scaled ----------------
// mode 0: bf16 out row-major MxN
// mode 1: fp32 out row-major MxN
// mode 2: bf16 out, V-transposed per head: out[((b*H+h)*DH+d)*QLEN + q]
__global__ __launch_bounds__(256) void gemm_bt(
    const bf16* __restrict__ A, const bf16* __restrict__ B,
    const float* __restrict__ bias, void* __restrict__ out,
    int M, int N, int K, float scale, int mode)
{
    __shared__ __align__(16) bf16 As[128*32];
    __shared__ __align__(16) bf16 Bs[128*32];

    const int t = threadIdx.x;
    const int lane = t & 63, w = t >> 6;
    const int row16 = lane & 15, quad = lane >> 4;
    const int m0 = blockIdx.y * 128, n0 = blockIdx.x * 128;
    const int mo = (w >> 1) * 64, no = (w & 1) * 64;

    f32x4 acc[4][4];
    for (int i = 0; i < 4; i++)
        for (int j = 0; j < 4; j++)
            acc[i][j] = (f32x4){0.f, 0.f, 0.f, 0.f};

    const int arow = t >> 2;          // 0..63
    const int achunk = (t & 3) * 8;   // 0,8,16,24

    for (int kt = 0; kt < K; kt += 32) {
        __syncthreads();
        gload_lds16(A + (size_t)(m0 + arow) * K + kt + achunk,      &As[arow*32 + achunk]);
        gload_lds16(A + (size_t)(m0 + 64 + arow) * K + kt + achunk, &As[(64+arow)*32 + achunk]);
        gload_lds16(B + (size_t)(n0 + arow) * K + kt + achunk,      &Bs[arow*32 + achunk]);
        gload_lds16(B + (size_t)(n0 + 64 + arow) * K + kt + achunk, &Bs[(64+arow)*32 + achunk]);
        __syncthreads();

        s16x8 af[4], bfr[4];
        for (int mt = 0; mt < 4; mt++)
            af[mt] = *(const s16x8*)&As[(mo + mt*16 + row16)*32 + quad*8];
        for (int nt = 0; nt < 4; nt++)
            bfr[nt] = *(const s16x8*)&Bs[(no + nt*16 + row16)*32 + quad*8];
        for (int mt = 0; mt < 4; mt++)
            for (int nt = 0; nt < 4; nt++)
                acc[mt][nt] = __builtin_amdgcn_mfma_f32_16x16x32_bf16(
                    af[mt], bfr[nt], acc[mt][nt], 0, 0, 0);
    }

    for (int mt = 0; mt < 4; mt++) {
        for (int nt = 0; nt < 4; nt++) {
            int n = n0 + no + nt*16 + row16;
            float bv = bias[n];
            for (int r = 0; r < 4; r++) {
                int m = m0 + mo + mt*16 + quad*4 + r;
                float v = (acc[mt][nt][r] + bv) * scale;
                if (mode == 0) {
                    ((bf16*)out)[(size_t)m * N + n] = __float2bfloat16(v);
                } else if (mode == 1) {
                    ((float*)out)[(size_t)m * N + n] = v;
                } else {
                    int b = m >> 11, q = m & 2047;     // QLEN=2048
                    int hh = n >> 7, d = n & 127;      // DH=128
                    ((bf16*)out)[(((size_t)b*H + hh)*DH + d)*QLEN + q] = __float2bfloat16(v);
                }
            }
        }
    }
}

// ---------------- flash attention: per wave 16 q rows, online softmax ----------------
__global__ __launch_bounds__(256) void attn(
    const bf16* __restrict__ Q, const bf16* __restrict__ Kb,
    const bf16* __restrict__ Vt, const int* __restrict__ mask,
    bf16* __restrict__ Ctx)
{
    __shared__ __align__(16) bf16 Pl[4][16*32];
    const int t = threadIdx.x, w = t >> 6, lane = t & 63;
    const int row16 = lane & 15, quad = lane >> 4;
    const int bh = blockIdx.y, b = bh >> 4, h = bh & 15;
    const int q0 = blockIdx.x * 64 + w * 16;

    // Q fragments for this wave's 16 rows (A-operand: m=lane&15, k=quad*8+j)
    s16x8 qf[4];
    const bf16* qp = Q + (size_t)(b*QLEN + q0 + row16) * DIM + h*DH;
    for (int ks = 0; ks < 4; ks++)
        qf[ks] = *(const s16x8*)(qp + ks*32 + quad*8);

    f32x4 o[8];
    for (int i = 0; i < 8; i++) o[i] = (f32x4){0.f, 0.f, 0.f, 0.f};
    float m_r[4] = {-1e30f, -1e30f, -1e30f, -1e30f};
    float l_r[4] = {0.f, 0.f, 0.f, 0.f};
    const int* mrow = mask + b * QLEN;

    for (int kt = 0; kt < QLEN; kt += 32) {
        f32x4 s0 = (f32x4){0,0,0,0}, s1 = (f32x4){0,0,0,0};
        const bf16* kp0 = Kb + (size_t)(b*QLEN + kt + row16) * DIM + h*DH;
        const bf16* kp1 = kp0 + (size_t)16 * DIM;
        for (int ks = 0; ks < 4; ks++) {
            s16x8 k0 = *(const s16x8*)(kp0 + ks*32 + quad*8);
            s16x8 k1 = *(const s16x8*)(kp1 + ks*32 + quad*8);
            s0 = __builtin_amdgcn_mfma_f32_16x16x32_bf16(qf[ks], k0, s0, 0, 0, 0);
            s1 = __builtin_amdgcn_mfma_f32_16x16x32_bf16(qf[ks], k1, s1, 0, 0, 0);
        }
        bool valid0 = mrow[kt + row16] != 0;
        bool valid1 = mrow[kt + 16 + row16] != 0;

        float alpha[4];
        for (int r = 0; r < 4; r++) {
            float v0 = valid0 ? s0[r] : -1e30f;
            float v1 = valid1 ? s1[r] : -1e30f;
            float tm = fmaxf(v0, v1);
            tm = fmaxf(tm, __shfl_xor(tm, 1));
            tm = fmaxf(tm, __shfl_xor(tm, 2));
            tm = fmaxf(tm, __shfl_xor(tm, 4));
            tm = fmaxf(tm, __shfl_xor(tm, 8));
            float mn = fmaxf(m_r[r], tm);
            float al = expf(m_r[r] - mn);
            m_r[r] = mn;
            alpha[r] = al;
            float p0 = expf(v0 - mn), p1 = expf(v1 - mn);
            float ts = p0 + p1;
            ts += __shfl_xor(ts, 1);
            ts += __shfl_xor(ts, 2);
            ts += __shfl_xor(ts, 4);
            ts += __shfl_xor(ts, 8);
            l_r[r] = l_r[r] * al + ts;
            // C-layout (row=quad*4+r, col=lane&15) -> LDS row-major 16x32
            Pl[w][(quad*4 + r)*32 + row16]      = __float2bfloat16(p0);
            Pl[w][(quad*4 + r)*32 + 16 + row16] = __float2bfloat16(p1);
        }
        for (int nt = 0; nt < 8; nt++)
            for (int r = 0; r < 4; r++) o[nt][r] *= alpha[r];

        __syncthreads();
        // A-operand read of P: m=lane&15 row, k=quad*8..+8
        s16x8 pf = *(const s16x8*)&Pl[w][row16*32 + quad*8];
        const bf16* vp = Vt + (size_t)(bh*DH + row16) * QLEN + kt + quad*8;
        for (int nt = 0; nt < 8; nt++) {
            s16x8 vf = *(const s16x8*)(vp + (size_t)nt * 16 * QLEN);
            o[nt] = __builtin_amdgcn_mfma_f32_16x16x32_bf16(pf, vf, o[nt], 0, 0, 0);
        }
        __syncthreads();
    }

    float inv[4];
    for (int r = 0; r < 4; r++) inv[r] = 1.0f / l_r[r];
    for (int nt = 0; nt < 8; nt++)
        for (int r = 0; r < 4; r++) {
            float v = o[nt][r] * inv[r];
            Ctx[(size_t)(b*QLEN + q0 + quad*4 + r) * DIM + h*DH + nt*16 + row16] =
                __float2bfloat16(v);
        }
}

extern "C" void kernel_launch(void* const* d_in, const int* in_sizes, int n_in,
                              void* d_out, int out_size, void* d_ws, size_t ws_size,
                              hipStream_t stream) {
    const float* x    = (const float*)d_in[0];
    const int*   mask = (const int*)d_in[1];
    const float* wq   = (const float*)d_in[2];
    const float* bq   = (const float*)d_in[3];
    const float* wk   = (const float*)d_in[4];
    const float* bk   = (const float*)d_in[5];
    const float* wv   = (const float*)d_in[6];
    const float* bv   = (const float*)d_in[7];
    const float* wo   = (const float*)d_in[8];
    const float* bo   = (const float*)d_in[9];

    char* ws = (char*)d_ws;
    const size_t MB = 1024 * 1024;
    bf16* Xb  = (bf16*)(ws);             // 16MB, later reused as Ctx
    bf16* Qb  = (bf16*)(ws + 16*MB);
    bf16* Kb  = (bf16*)(ws + 32*MB);
    bf16* Vtb = (bf16*)(ws + 48*MB);
    bf16* Wqb = (bf16*)(ws + 64*MB);
    bf16* Wkb = (bf16*)(ws + 72*MB);
    bf16* Wvb = (bf16*)(ws + 80*MB);
    bf16* Wob = (bf16*)(ws + 88*MB);
    bf16* Ctx = Xb;

    int n4x = (BS*QLEN*DIM) / 4;   // 2,097,152 -> 8192 blocks
    int n4w = (DIM*DIM) / 4;       // 1,048,576 -> 4096 blocks
    cast_kernel<<<dim3(n4x/256), 256, 0, stream>>>(x,  Xb,  n4x);
    cast_kernel<<<dim3(n4w/256), 256, 0, stream>>>(wq, Wqb, n4w);
    cast_kernel<<<dim3(n4w/256), 256, 0, stream>>>(wk, Wkb, n4w);
    cast_kernel<<<dim3(n4w/256), 256, 0, stream>>>(wv, Wvb, n4w);
    cast_kernel<<<dim3(n4w/256), 256, 0, stream>>>(wo, Wob, n4w);

    dim3 gg(DIM/128, MTOT/128);    // (16, 32)
    const float qscale = 0.08838834764831845f;  // 1/sqrt(128)
    gemm_bt<<<gg, 256, 0, stream>>>(Xb, Wqb, bq, Qb,  MTOT, DIM, DIM, qscale, 0);
    gemm_bt<<<gg, 256, 0, stream>>>(Xb, Wkb, bk, Kb,  MTOT, DIM, DIM, 1.0f,   0);
    gemm_bt<<<gg, 256, 0, stream>>>(Xb, Wvb, bv, Vtb, MTOT, DIM, DIM, 1.0f,   2);

    attn<<<dim3(QLEN/64, BS*H), 256, 0, stream>>>(Qb, Kb, Vtb, mask, Ctx);

    gemm_bt<<<gg, 256, 0, stream>>>(Ctx, Wob, bo, d_out, MTOT, DIM, DIM, 1.0f, 1);
}

// Round 2
// 1006.766 us; speedup vs baseline: 1.8609x; 1.8609x over previous
//
#include <hip/hip_runtime.h>
#include <hip/hip_bf16.h>

#define BS 2
#define QLEN 2048
#define DIM 2048
#define H 16
#define DH 128
#define MTOT (BS*QLEN)

typedef __hip_bfloat16 bf16;
using f32x4 = __attribute__((ext_vector_type(4))) float;
using s16x8 = __attribute__((ext_vector_type(8))) short;

__device__ inline void gload_lds16(const bf16* g, bf16* l) {
    __builtin_amdgcn_global_load_lds(
        (const __attribute__((address_space(1))) void*)g,
        (__attribute__((address_space(3))) void*)l,
        16, 0, 0);
}

// ---------------- fp32 -> bf16 cast ----------------
__global__ __launch_bounds__(256) void cast_kernel(const float* __restrict__ in,
                                                   bf16* __restrict__ out, int n4) {
    int i = blockIdx.x * 256 + threadIdx.x;
    if (i < n4) {
        float4 v = ((const float4*)in)[i];
        __hip_bfloat162 p0 = __float22bfloat162_rn(make_float2(v.x, v.y));
        __hip_bfloat162 p1 = __float22bfloat162_rn(make_float2(v.z, v.w));
        ((__hip_bfloat162*)out)[2*i]   = p0;
        ((__hip_bfloat162*)out)[2*i+1] = p1;
    }
}

// ---------------- GEMM: C = (A(MxK) * B(NxK)^T + bias) * scale ----------------
// MODE 0: bf16 out row-major MxN
// MODE 1: fp32 out row-major MxN
// MODE 2: bf16 out, transposed: out[(b*DIM + n)*QLEN + q]  (for V^T)
template<int MODE>
__global__ __launch_bounds__(256) void gemm_bt(
    const bf16* __restrict__ A, const bf16* __restrict__ B,
    const float* __restrict__ bias, void* __restrict__ out,
    int M, int N, int K, float scale)
{
    __shared__ __align__(16) bf16 As[128*32];
    __shared__ __align__(16) bf16 Bs[128*32];

    const int t = threadIdx.x;
    const int lane = t & 63, w = t >> 6;
    const int row16 = lane & 15, quad = lane >> 4;
    const int m0 = blockIdx.y * 128, n0 = blockIdx.x * 128;
    const int mo = (w >> 1) * 64, no = (w & 1) * 64;

    f32x4 acc[4][4];
    for (int i = 0; i < 4; i++)
        for (int j = 0; j < 4; j++)
            acc[i][j] = (f32x4){0.f, 0.f, 0.f, 0.f};

    const int arow = t >> 2;
    const int achunk = (t & 3) * 8;

    for (int kt = 0; kt < K; kt += 32) {
        __syncthreads();
        gload_lds16(A + (size_t)(m0 + arow) * K + kt + achunk,      &As[arow*32 + achunk]);
        gload_lds16(A + (size_t)(m0 + 64 + arow) * K + kt + achunk, &As[(64+arow)*32 + achunk]);
        gload_lds16(B + (size_t)(n0 + arow) * K + kt + achunk,      &Bs[arow*32 + achunk]);
        gload_lds16(B + (size_t)(n0 + 64 + arow) * K + kt + achunk, &Bs[(64+arow)*32 + achunk]);
        __syncthreads();

        s16x8 af[4], bfr[4];
        for (int mt = 0; mt < 4; mt++)
            af[mt] = *(const s16x8*)&As[(mo + mt*16 + row16)*32 + quad*8];
        for (int nt = 0; nt < 4; nt++)
            bfr[nt] = *(const s16x8*)&Bs[(no + nt*16 + row16)*32 + quad*8];
        for (int mt = 0; mt < 4; mt++)
            for (int nt = 0; nt < 4; nt++)
                acc[mt][nt] = __builtin_amdgcn_mfma_f32_16x16x32_bf16(
                    af[mt], bfr[nt], acc[mt][nt], 0, 0, 0);
    }

    if constexpr (MODE == 2) {
        // transpose bounce through LDS, then coalesced 16B stores along q
        __shared__ __align__(16) bf16 Ts[128*136];
        for (int mt = 0; mt < 4; mt++)
            for (int nt = 0; nt < 4; nt++) {
                int nn = no + nt*16 + row16;
                float bv = bias[n0 + nn];
                for (int r = 0; r < 4; r++) {
                    int mm = mo + mt*16 + quad*4 + r;
                    Ts[nn*136 + mm] = __float2bfloat16((acc[mt][nt][r] + bv) * scale);
                }
            }
        __syncthreads();
        const int b = m0 >> 11, q0b = m0 & 2047;   // QLEN=2048
        for (int i = 0; i < 8; i++) {
            int chunk = t + i*256;     // 0..2047
            int row = chunk >> 4;      // n-local 0..127
            int c16 = chunk & 15;      // 16B chunk in 256B row
            s16x8 val = *(const s16x8*)&Ts[row*136 + c16*8];
            *(s16x8*)((bf16*)out + ((size_t)(b*DIM + n0 + row))*QLEN + q0b + c16*8) = val;
        }
    } else {
        for (int mt = 0; mt < 4; mt++)
            for (int nt = 0; nt < 4; nt++) {
                int n = n0 + no + nt*16 + row16;
                float bv = bias[n];
                for (int r = 0; r < 4; r++) {
                    int m = m0 + mo + mt*16 + quad*4 + r;
                    float v = (acc[mt][nt][r] + bv) * scale;
                    if constexpr (MODE == 0)
                        ((bf16*)out)[(size_t)m * N + n] = __float2bfloat16(v);
                    else
                        ((float*)out)[(size_t)m * N + n] = v;
                }
            }
    }
}

// ---------------- flash attention: barrier-free, KT=128, exp2 ----------------
// Q pre-scaled by log2(e)/sqrt(DH). Vt layout: [(b*DIM + h*DH + d)*QLEN + k].
__global__ __launch_bounds__(256, 3) void attn(
    const bf16* __restrict__ Q, const bf16* __restrict__ Kb,
    const bf16* __restrict__ Vt, const int* __restrict__ mask,
    bf16* __restrict__ Ctx)
{
    __shared__ __align__(16) bf16 Pl[4][16*136];   // per-wave, stride 136 (pad)
    const int t = threadIdx.x, w = t >> 6, lane = t & 63;
    const int row16 = lane & 15, quad = lane >> 4;
    const int bh = blockIdx.y, b = bh >> 4, h = bh & 15;
    const int q0 = blockIdx.x * 64 + w * 16;

    // Q A-fragments (m=lane&15 row, k=quad*8+j)
    s16x8 qf[4];
    const bf16* qp = Q + (size_t)(b*QLEN + q0 + row16) * DIM + h*DH;
    for (int ks = 0; ks < 4; ks++)
        qf[ks] = *(const s16x8*)(qp + ks*32 + quad*8);

    f32x4 o[8];
    for (int i = 0; i < 8; i++) o[i] = (f32x4){0.f, 0.f, 0.f, 0.f};
    float m_r[4] = {-1e30f, -1e30f, -1e30f, -1e30f};
    float l_r[4] = {0.f, 0.f, 0.f, 0.f};
    const int* mrow = mask + b * QLEN;

    for (int kt = 0; kt < QLEN; kt += 128) {
        // ---- scores: 16 q-rows x 128 k-cols ----
        f32x4 s[8];
        for (int nt = 0; nt < 8; nt++) s[nt] = (f32x4){0.f, 0.f, 0.f, 0.f};
        const bf16* kp = Kb + (size_t)(b*QLEN + kt + row16) * DIM + h*DH + quad*8;
        for (int ks = 0; ks < 4; ks++)
            for (int nt = 0; nt < 8; nt++) {
                s16x8 kf = *(const s16x8*)(kp + (size_t)(nt*16) * DIM + ks*32);
                s[nt] = __builtin_amdgcn_mfma_f32_16x16x32_bf16(qf[ks], kf, s[nt], 0, 0, 0);
            }

        float mval[8];
        for (int nt = 0; nt < 8; nt++)
            mval[nt] = (mrow[kt + nt*16 + row16] != 0) ? 0.f : -1e30f;

        // ---- online softmax (log2 domain), one update per 128 cols ----
        float alpha[4];
        for (int r = 0; r < 4; r++) {
            float v[8];
            for (int nt = 0; nt < 8; nt++) v[nt] = s[nt][r] + mval[nt];
            float tm = v[0];
            for (int nt = 1; nt < 8; nt++) tm = fmaxf(tm, v[nt]);
            tm = fmaxf(tm, __shfl_xor(tm, 1));
            tm = fmaxf(tm, __shfl_xor(tm, 2));
            tm = fmaxf(tm, __shfl_xor(tm, 4));
            tm = fmaxf(tm, __shfl_xor(tm, 8));
            float mn = fmaxf(m_r[r], tm);
            alpha[r] = exp2f(m_r[r] - mn);
            m_r[r] = mn;
            float ts = 0.f;
            for (int nt = 0; nt < 8; nt++) {
                float p = exp2f(v[nt] - mn);
                ts += p;
                Pl[w][(quad*4 + r)*136 + nt*16 + row16] = __float2bfloat16(p);
            }
            ts += __shfl_xor(ts, 1);
            ts += __shfl_xor(ts, 2);
            ts += __shfl_xor(ts, 4);
            ts += __shfl_xor(ts, 8);
            l_r[r] = l_r[r] * alpha[r] + ts;
        }
        for (int nt = 0; nt < 8; nt++)
            for (int r = 0; r < 4; r++) o[nt][r] *= alpha[r];

        // ---- PV: P (A-op from LDS) x Vt (B-op from global) ----
        const bf16* vp = Vt + (size_t)(b*DIM + h*DH + row16) * QLEN + kt + quad*8;
        for (int c = 0; c < 4; c++) {
            s16x8 pf = *(const s16x8*)&Pl[w][row16*136 + c*32 + quad*8];
            for (int nt = 0; nt < 8; nt++) {
                s16x8 vf = *(const s16x8*)(vp + (size_t)(nt*16) * QLEN + c*32);
                o[nt] = __builtin_amdgcn_mfma_f32_16x16x32_bf16(pf, vf, o[nt], 0, 0, 0);
            }
        }
    }

    float inv[4];
    for (int r = 0; r < 4; r++) inv[r] = 1.0f / l_r[r];
    for (int nt = 0; nt < 8; nt++)
        for (int r = 0; r < 4; r++) {
            float v = o[nt][r] * inv[r];
            Ctx[(size_t)(b*QLEN + q0 + quad*4 + r) * DIM + h*DH + nt*16 + row16] =
                __float2bfloat16(v);
        }
}

extern "C" void kernel_launch(void* const* d_in, const int* in_sizes, int n_in,
                              void* d_out, int out_size, void* d_ws, size_t ws_size,
                              hipStream_t stream) {
    const float* x    = (const float*)d_in[0];
    const int*   mask = (const int*)d_in[1];
    const float* wq   = (const float*)d_in[2];
    const float* bq   = (const float*)d_in[3];
    const float* wk   = (const float*)d_in[4];
    const float* bk   = (const float*)d_in[5];
    const float* wv   = (const float*)d_in[6];
    const float* bv   = (const float*)d_in[7];
    const float* wo   = (const float*)d_in[8];
    const float* bo   = (const float*)d_in[9];

    char* ws = (char*)d_ws;
    const size_t MB = 1024 * 1024;
    bf16* Xb  = (bf16*)(ws);             // 16MB, later reused as Ctx
    bf16* Qb  = (bf16*)(ws + 16*MB);
    bf16* Kb  = (bf16*)(ws + 32*MB);
    bf16* Vtb = (bf16*)(ws + 48*MB);
    bf16* Wqb = (bf16*)(ws + 64*MB);
    bf16* Wkb = (bf16*)(ws + 72*MB);
    bf16* Wvb = (bf16*)(ws + 80*MB);
    bf16* Wob = (bf16*)(ws + 88*MB);
    bf16* Ctx = Xb;

    int n4x = (BS*QLEN*DIM) / 4;
    int n4w = (DIM*DIM) / 4;
    cast_kernel<<<dim3(n4x/256), 256, 0, stream>>>(x,  Xb,  n4x);
    cast_kernel<<<dim3(n4w/256), 256, 0, stream>>>(wq, Wqb, n4w);
    cast_kernel<<<dim3(n4w/256), 256, 0, stream>>>(wk, Wkb, n4w);
    cast_kernel<<<dim3(n4w/256), 256, 0, stream>>>(wv, Wvb, n4w);
    cast_kernel<<<dim3(n4w/256), 256, 0, stream>>>(wo, Wob, n4w);

    dim3 gg(DIM/128, MTOT/128);    // (16, 32)
    // 1/sqrt(128) * log2(e): scores land in log2 domain for exp2-softmax
    const float qscale = 0.08838834764831845f * 1.4426950408889634f;
    gemm_bt<0><<<gg, 256, 0, stream>>>(Xb, Wqb, bq, Qb,  MTOT, DIM, DIM, qscale);
    gemm_bt<0><<<gg, 256, 0, stream>>>(Xb, Wkb, bk, Kb,  MTOT, DIM, DIM, 1.0f);
    gemm_bt<2><<<gg, 256, 0, stream>>>(Xb, Wvb, bv, Vtb, MTOT, DIM, DIM, 1.0f);

    attn<<<dim3(QLEN/64, BS*H), 256, 0, stream>>>(Qb, Kb, Vtb, mask, Ctx);

    gemm_bt<1><<<gg, 256, 0, stream>>>(Ctx, Wob, bo, d_out, MTOT, DIM, DIM, 1.0f);
}

// Round 3
// 529.021 us; speedup vs baseline: 3.5414x; 1.9031x over previous
//
#include <hip/hip_runtime.h>
#include <hip/hip_bf16.h>

#define BS 2
#define QLEN 2048
#define DIM 2048
#define H 16
#define DH 128
#define MTOT (BS*QLEN)

typedef __hip_bfloat16 bf16;
using f32x4 = __attribute__((ext_vector_type(4))) float;
using s16x8 = __attribute__((ext_vector_type(8))) short;

__device__ inline void gload_lds16(const bf16* g, bf16* l) {
    __builtin_amdgcn_global_load_lds(
        (const __attribute__((address_space(1))) void*)g,
        (__attribute__((address_space(3))) void*)l,
        16, 0, 0);
}

// ---------------- fp32 -> bf16 cast ----------------
__global__ __launch_bounds__(256) void cast_kernel(const float* __restrict__ in,
                                                   bf16* __restrict__ out, int n4) {
    int i = blockIdx.x * 256 + threadIdx.x;
    if (i < n4) {
        float4 v = ((const float4*)in)[i];
        __hip_bfloat162 p0 = __float22bfloat162_rn(make_float2(v.x, v.y));
        __hip_bfloat162 p1 = __float22bfloat162_rn(make_float2(v.z, v.w));
        ((__hip_bfloat162*)out)[2*i]   = p0;
        ((__hip_bfloat162*)out)[2*i+1] = p1;
    }
}

// ---------------- GEMM: C = (A(MxK) * B(NxK)^T + bias) * scale ----------------
// MODE 0: bf16 out row-major MxN
// MODE 1: fp32 out row-major MxN
// MODE 2: bf16 out, transposed: out[(b*DIM + n)*QLEN + q]  (for V^T)
template<int MODE>
__global__ __launch_bounds__(256) void gemm_bt(
    const bf16* __restrict__ A, const bf16* __restrict__ B,
    const float* __restrict__ bias, void* __restrict__ out,
    int M, int N, int K, float scale)
{
    __shared__ __align__(16) bf16 As[128*32];
    __shared__ __align__(16) bf16 Bs[128*32];

    const int t = threadIdx.x;
    const int lane = t & 63, w = t >> 6;
    const int row16 = lane & 15, quad = lane >> 4;
    const int m0 = blockIdx.y * 128, n0 = blockIdx.x * 128;
    const int mo = (w >> 1) * 64, no = (w & 1) * 64;

    f32x4 acc[4][4];
    for (int i = 0; i < 4; i++)
        for (int j = 0; j < 4; j++)
            acc[i][j] = (f32x4){0.f, 0.f, 0.f, 0.f};

    const int arow = t >> 2;
    const int achunk = (t & 3) * 8;

    for (int kt = 0; kt < K; kt += 32) {
        __syncthreads();
        gload_lds16(A + (size_t)(m0 + arow) * K + kt + achunk,      &As[arow*32 + achunk]);
        gload_lds16(A + (size_t)(m0 + 64 + arow) * K + kt + achunk, &As[(64+arow)*32 + achunk]);
        gload_lds16(B + (size_t)(n0 + arow) * K + kt + achunk,      &Bs[arow*32 + achunk]);
        gload_lds16(B + (size_t)(n0 + 64 + arow) * K + kt + achunk, &Bs[(64+arow)*32 + achunk]);
        __syncthreads();

        s16x8 af[4], bfr[4];
        for (int mt = 0; mt < 4; mt++)
            af[mt] = *(const s16x8*)&As[(mo + mt*16 + row16)*32 + quad*8];
        for (int nt = 0; nt < 4; nt++)
            bfr[nt] = *(const s16x8*)&Bs[(no + nt*16 + row16)*32 + quad*8];
        for (int mt = 0; mt < 4; mt++)
            for (int nt = 0; nt < 4; nt++)
                acc[mt][nt] = __builtin_amdgcn_mfma_f32_16x16x32_bf16(
                    af[mt], bfr[nt], acc[mt][nt], 0, 0, 0);
    }

    if constexpr (MODE == 2) {
        __shared__ __align__(16) bf16 Ts[128*136];
        for (int mt = 0; mt < 4; mt++)
            for (int nt = 0; nt < 4; nt++) {
                int nn = no + nt*16 + row16;
                float bv = bias[n0 + nn];
                for (int r = 0; r < 4; r++) {
                    int mm = mo + mt*16 + quad*4 + r;
                    Ts[nn*136 + mm] = __float2bfloat16((acc[mt][nt][r] + bv) * scale);
                }
            }
        __syncthreads();
        const int b = m0 >> 11, q0b = m0 & 2047;
        for (int i = 0; i < 8; i++) {
            int chunk = t + i*256;
            int row = chunk >> 4;
            int c16 = chunk & 15;
            s16x8 val = *(const s16x8*)&Ts[row*136 + c16*8];
            *(s16x8*)((bf16*)out + ((size_t)(b*DIM + n0 + row))*QLEN + q0b + c16*8) = val;
        }
    } else {
        for (int mt = 0; mt < 4; mt++)
            for (int nt = 0; nt < 4; nt++) {
                int n = n0 + no + nt*16 + row16;
                float bv = bias[n];
                for (int r = 0; r < 4; r++) {
                    int m = m0 + mo + mt*16 + quad*4 + r;
                    float v = (acc[mt][nt][r] + bv) * scale;
                    if constexpr (MODE == 0)
                        ((bf16*)out)[(size_t)m * N + n] = __float2bfloat16(v);
                    else
                        ((float*)out)[(size_t)m * N + n] = v;
                }
            }
    }
}

// ---------------- flash attention: LDS-staged K/V, 32 q-rows/wave ----------------
// Q pre-scaled by log2(e)/sqrt(DH). Vt layout: [(b*DIM + h*DH + d)*QLEN + k].
// K tile in LDS: Ks[r][c-chunk] with XOR swizzle c = g ^ (r&15)  (16 chunks/row)
// V tile in LDS: Vs[d][c-chunk] with XOR swizzle c = g ^ (d&7)   (8 chunks/row)
__global__ __launch_bounds__(256, 2) void attn(
    const bf16* __restrict__ Q, const bf16* __restrict__ Kb,
    const bf16* __restrict__ Vt, const int* __restrict__ mask,
    bf16* __restrict__ Ctx)
{
    __shared__ __align__(16) bf16 Ks[64*128];     // 16 KB
    __shared__ __align__(16) bf16 Vs[128*64];     // 16 KB
    __shared__ __align__(16) bf16 Pl[4][32*72];   // per-wave P, stride 72 (18 KB)

    const int t = threadIdx.x, w = t >> 6, lane = t & 63;
    const int row16 = lane & 15, quad = lane >> 4;
    const int bh = blockIdx.y, b = bh >> 4, h = bh & 15;
    const int q0 = blockIdx.x * 128 + w * 32;

    // Q A-fragments for 2 row-sets of 16 (m=lane&15, k=quad*8+j)
    s16x8 qf[2][4];
    for (int qs = 0; qs < 2; qs++) {
        const bf16* qp = Q + (size_t)(b*QLEN + q0 + qs*16 + row16) * DIM + h*DH;
        for (int ks = 0; ks < 4; ks++)
            qf[qs][ks] = *(const s16x8*)(qp + ks*32 + quad*8);
    }

    f32x4 o[2][8];
    for (int qs = 0; qs < 2; qs++)
        for (int i = 0; i < 8; i++) o[qs][i] = (f32x4){0.f, 0.f, 0.f, 0.f};
    float m_r[2][4], l_r[2][4];
    for (int qs = 0; qs < 2; qs++)
        for (int r = 0; r < 4; r++) { m_r[qs][r] = -1e30f; l_r[qs][r] = 0.f; }
    const int* mrow = mask + b * QLEN;

    // staging geometry (per thread, 4 issues each for K and V)
    // K: idx = (w*4+i)*64 + lane; r = idx>>4, c = idx&15, src chunk g = c ^ (r&15)
    // V: idx = (w*4+i)*64 + lane; d = idx>>3, c = idx&7,  src chunk g = c ^ (d&7)
    const bf16* Kbase = Kb + (size_t)b*QLEN*DIM + h*DH;
    const bf16* Vbase = Vt + ((size_t)b*DIM + h*DH) * QLEN;

    for (int kt = 0; kt < QLEN; kt += 64) {
        __syncthreads();
        #pragma unroll
        for (int i = 0; i < 4; i++) {
            int idx = (w*4 + i)*64 + lane;
            int kr = idx >> 4, kc = idx & 15;
            int kg = kc ^ (kr & 15);
            gload_lds16(Kbase + (size_t)(kt + kr) * DIM + kg*8, &Ks[idx*8]);
            int vd = idx >> 3, vc = idx & 7;
            int vg = vc ^ (vd & 7);
            gload_lds16(Vbase + (size_t)vd * QLEN + kt + vg*8, &Vs[idx*8]);
        }
        __syncthreads();

        // ---- scores: 32 q-rows x 64 k-cols ----
        f32x4 sc[2][4];
        for (int qs = 0; qs < 2; qs++)
            for (int nt = 0; nt < 4; nt++) sc[qs][nt] = (f32x4){0.f, 0.f, 0.f, 0.f};
        #pragma unroll
        for (int ks = 0; ks < 4; ks++) {
            #pragma unroll
            for (int nt = 0; nt < 4; nt++) {
                int rrow = nt*16 + row16;
                int c = (ks*4 + quad) ^ row16;
                s16x8 kf = *(const s16x8*)&Ks[rrow*128 + c*8];
                sc[0][nt] = __builtin_amdgcn_mfma_f32_16x16x32_bf16(qf[0][ks], kf, sc[0][nt], 0, 0, 0);
                sc[1][nt] = __builtin_amdgcn_mfma_f32_16x16x32_bf16(qf[1][ks], kf, sc[1][nt], 0, 0, 0);
            }
        }

        float mval[4];
        #pragma unroll
        for (int nt = 0; nt < 4; nt++)
            mval[nt] = (mrow[kt + nt*16 + row16] != 0) ? 0.f : -1e30f;

        // ---- online softmax (log2 domain) ----
        #pragma unroll
        for (int qs = 0; qs < 2; qs++) {
            #pragma unroll
            for (int r = 0; r < 4; r++) {
                float v[4];
                for (int nt = 0; nt < 4; nt++) v[nt] = sc[qs][nt][r] + mval[nt];
                float tm = fmaxf(fmaxf(v[0], v[1]), fmaxf(v[2], v[3]));
                tm = fmaxf(tm, __shfl_xor(tm, 1));
                tm = fmaxf(tm, __shfl_xor(tm, 2));
                tm = fmaxf(tm, __shfl_xor(tm, 4));
                tm = fmaxf(tm, __shfl_xor(tm, 8));
                float mn = fmaxf(m_r[qs][r], tm);
                float alpha = exp2f(m_r[qs][r] - mn);
                m_r[qs][r] = mn;
                float ts = 0.f;
                for (int nt = 0; nt < 4; nt++) {
                    float p = exp2f(v[nt] - mn);
                    ts += p;
                    Pl[w][(qs*16 + quad*4 + r)*72 + nt*16 + row16] = __float2bfloat16(p);
                }
                ts += __shfl_xor(ts, 1);
                ts += __shfl_xor(ts, 2);
                ts += __shfl_xor(ts, 4);
                ts += __shfl_xor(ts, 8);
                l_r[qs][r] = l_r[qs][r] * alpha + ts;
                for (int nt = 0; nt < 8; nt++) o[qs][nt][r] *= alpha;
            }
        }

        // ---- PV: P (A-op, per-wave LDS) x V (B-op, swizzled LDS) ----
        #pragma unroll
        for (int kc = 0; kc < 2; kc++) {
            s16x8 pf0 = *(const s16x8*)&Pl[w][(0*16 + row16)*72 + kc*32 + quad*8];
            s16x8 pf1 = *(const s16x8*)&Pl[w][(1*16 + row16)*72 + kc*32 + quad*8];
            #pragma unroll
            for (int nt = 0; nt < 8; nt++) {
                int d = nt*16 + row16;
                int c = (kc*4 + quad) ^ (d & 7);
                s16x8 vf = *(const s16x8*)&Vs[d*64 + c*8];
                o[0][nt] = __builtin_amdgcn_mfma_f32_16x16x32_bf16(pf0, vf, o[0][nt], 0, 0, 0);
                o[1][nt] = __builtin_amdgcn_mfma_f32_16x16x32_bf16(pf1, vf, o[1][nt], 0, 0, 0);
            }
        }
    }

    for (int qs = 0; qs < 2; qs++) {
        float inv[4];
        for (int r = 0; r < 4; r++) inv[r] = 1.0f / l_r[qs][r];
        for (int nt = 0; nt < 8; nt++)
            for (int r = 0; r < 4; r++) {
                float v = o[qs][nt][r] * inv[r];
                Ctx[(size_t)(b*QLEN + q0 + qs*16 + quad*4 + r) * DIM + h*DH + nt*16 + row16] =
                    __float2bfloat16(v);
            }
    }
}

extern "C" void kernel_launch(void* const* d_in, const int* in_sizes, int n_in,
                              void* d_out, int out_size, void* d_ws, size_t ws_size,
                              hipStream_t stream) {
    const float* x    = (const float*)d_in[0];
    const int*   mask = (const int*)d_in[1];
    const float* wq   = (const float*)d_in[2];
    const float* bq   = (const float*)d_in[3];
    const float* wk   = (const float*)d_in[4];
    const float* bk   = (const float*)d_in[5];
    const float* wv   = (const float*)d_in[6];
    const float* bv   = (const float*)d_in[7];
    const float* wo   = (const float*)d_in[8];
    const float* bo   = (const float*)d_in[9];

    char* ws = (char*)d_ws;
    const size_t MB = 1024 * 1024;
    bf16* Xb  = (bf16*)(ws);             // 16MB, later reused as Ctx
    bf16* Qb  = (bf16*)(ws + 16*MB);
    bf16* Kb  = (bf16*)(ws + 32*MB);
    bf16* Vtb = (bf16*)(ws + 48*MB);
    bf16* Wqb = (bf16*)(ws + 64*MB);
    bf16* Wkb = (bf16*)(ws + 72*MB);
    bf16* Wvb = (bf16*)(ws + 80*MB);
    bf16* Wob = (bf16*)(ws + 88*MB);
    bf16* Ctx = Xb;

    int n4x = (BS*QLEN*DIM) / 4;
    int n4w = (DIM*DIM) / 4;
    cast_kernel<<<dim3(n4x/256), 256, 0, stream>>>(x,  Xb,  n4x);
    cast_kernel<<<dim3(n4w/256), 256, 0, stream>>>(wq, Wqb, n4w);
    cast_kernel<<<dim3(n4w/256), 256, 0, stream>>>(wk, Wkb, n4w);
    cast_kernel<<<dim3(n4w/256), 256, 0, stream>>>(wv, Wvb, n4w);
    cast_kernel<<<dim3(n4w/256), 256, 0, stream>>>(wo, Wob, n4w);

    dim3 gg(DIM/128, MTOT/128);    // (16, 32)
    const float qscale = 0.08838834764831845f * 1.4426950408889634f;
    gemm_bt<0><<<gg, 256, 0, stream>>>(Xb, Wqb, bq, Qb,  MTOT, DIM, DIM, qscale);
    gemm_bt<0><<<gg, 256, 0, stream>>>(Xb, Wkb, bk, Kb,  MTOT, DIM, DIM, 1.0f);
    gemm_bt<2><<<gg, 256, 0, stream>>>(Xb, Wvb, bv, Vtb, MTOT, DIM, DIM, 1.0f);

    attn<<<dim3(QLEN/128, BS*H), 256, 0, stream>>>(Qb, Kb, Vtb, mask, Ctx);

    gemm_bt<1><<<gg, 256, 0, stream>>>(Ctx, Wob, bo, d_out, MTOT, DIM, DIM, 1.0f);
}

// Round 4
// 424.431 us; speedup vs baseline: 4.4140x; 1.2464x over previous
//
#include <hip/hip_runtime.h>
#include <hip/hip_bf16.h>

#define BS 2
#define QLEN 2048
#define DIM 2048
#define H 16
#define DH 128
#define MTOT (BS*QLEN)

typedef __hip_bfloat16 bf16;
using f32x4 = __attribute__((ext_vector_type(4))) float;
using s16x8 = __attribute__((ext_vector_type(8))) short;

__device__ inline void gload_lds16(const bf16* g, bf16* l) {
    __builtin_amdgcn_global_load_lds(
        (const __attribute__((address_space(1))) void*)g,
        (__attribute__((address_space(3))) void*)l,
        16, 0, 0);
}

// ---------------- fp32 -> bf16 casts ----------------
__global__ __launch_bounds__(256) void cast_kernel(const float* __restrict__ in,
                                                   bf16* __restrict__ out, int n4) {
    int i = blockIdx.x * 256 + threadIdx.x;
    if (i < n4) {
        float4 v = ((const float4*)in)[i];
        __hip_bfloat162 p0 = __float22bfloat162_rn(make_float2(v.x, v.y));
        __hip_bfloat162 p1 = __float22bfloat162_rn(make_float2(v.z, v.w));
        ((__hip_bfloat162*)out)[2*i]   = p0;
        ((__hip_bfloat162*)out)[2*i+1] = p1;
    }
}

__global__ __launch_bounds__(256) void cast_w4(
    const float* __restrict__ w0, const float* __restrict__ w1,
    const float* __restrict__ w2, const float* __restrict__ w3,
    bf16* o0, bf16* o1, bf16* o2, bf16* o3, int n4)
{
    const float* in; bf16* out;
    switch (blockIdx.y) {
        case 0:  in = w0; out = o0; break;
        case 1:  in = w1; out = o1; break;
        case 2:  in = w2; out = o2; break;
        default: in = w3; out = o3; break;
    }
    int i = blockIdx.x * 256 + threadIdx.x;
    if (i < n4) {
        float4 v = ((const float4*)in)[i];
        __hip_bfloat162 p0 = __float22bfloat162_rn(make_float2(v.x, v.y));
        __hip_bfloat162 p1 = __float22bfloat162_rn(make_float2(v.z, v.w));
        ((__hip_bfloat162*)out)[2*i]   = p0;
        ((__hip_bfloat162*)out)[2*i+1] = p1;
    }
}

// ---------------- fused Q/K/V projection GEMM (z selects weight) ----------------
// C = (A * W^T + bias) * scale.  z=0: Q (scaled, row-major). z=1: K (row-major).
// z=2: V, transposed out[(b*DIM + n)*QLEN + q].
__global__ __launch_bounds__(256) void gemm_qkv(
    const bf16* __restrict__ A,
    const bf16* __restrict__ Wq, const bf16* __restrict__ Wk, const bf16* __restrict__ Wv,
    const float* __restrict__ bq, const float* __restrict__ bk, const float* __restrict__ bv,
    bf16* __restrict__ Qo, bf16* __restrict__ Ko, bf16* __restrict__ Vo,
    float qscale)
{
    __shared__ __align__(16) bf16 smem[128*136];   // As/Bs arena; reused as Ts in z=2 epilogue
    bf16* As = smem;
    bf16* Bs = smem + 128*32;

    const int z = blockIdx.z;
    const bf16*  B    = (z == 0) ? Wq : (z == 1) ? Wk : Wv;
    const float* bias = (z == 0) ? bq : (z == 1) ? bk : bv;
    const float  scale = (z == 0) ? qscale : 1.0f;

    const int t = threadIdx.x;
    const int lane = t & 63, w = t >> 6;
    const int row16 = lane & 15, quad = lane >> 4;
    const int m0 = blockIdx.y * 128, n0 = blockIdx.x * 128;
    const int mo = (w >> 1) * 64, no = (w & 1) * 64;

    f32x4 acc[4][4];
    for (int i = 0; i < 4; i++)
        for (int j = 0; j < 4; j++)
            acc[i][j] = (f32x4){0.f, 0.f, 0.f, 0.f};

    const int arow = t >> 2;
    const int achunk = (t & 3) * 8;

    for (int kt = 0; kt < DIM; kt += 32) {
        __syncthreads();
        gload_lds16(A + (size_t)(m0 + arow) * DIM + kt + achunk,      &As[arow*32 + achunk]);
        gload_lds16(A + (size_t)(m0 + 64 + arow) * DIM + kt + achunk, &As[(64+arow)*32 + achunk]);
        gload_lds16(B + (size_t)(n0 + arow) * DIM + kt + achunk,      &Bs[arow*32 + achunk]);
        gload_lds16(B + (size_t)(n0 + 64 + arow) * DIM + kt + achunk, &Bs[(64+arow)*32 + achunk]);
        __syncthreads();

        s16x8 af[4], bfr[4];
        for (int mt = 0; mt < 4; mt++)
            af[mt] = *(const s16x8*)&As[(mo + mt*16 + row16)*32 + quad*8];
        for (int nt = 0; nt < 4; nt++)
            bfr[nt] = *(const s16x8*)&Bs[(no + nt*16 + row16)*32 + quad*8];
        for (int mt = 0; mt < 4; mt++)
            for (int nt = 0; nt < 4; nt++)
                acc[mt][nt] = __builtin_amdgcn_mfma_f32_16x16x32_bf16(
                    af[mt], bfr[nt], acc[mt][nt], 0, 0, 0);
    }

    if (z < 2) {
        bf16* out = (z == 0) ? Qo : Ko;
        for (int mt = 0; mt < 4; mt++)
            for (int nt = 0; nt < 4; nt++) {
                int n = n0 + no + nt*16 + row16;
                float bv_ = bias[n];
                for (int r = 0; r < 4; r++) {
                    int m = m0 + mo + mt*16 + quad*4 + r;
                    out[(size_t)m * DIM + n] = __float2bfloat16((acc[mt][nt][r] + bv_) * scale);
                }
            }
    } else {
        __syncthreads();                 // As/Bs dead for ALL waves before Ts reuse
        bf16* Ts = smem;                 // 128*136
        for (int mt = 0; mt < 4; mt++)
            for (int nt = 0; nt < 4; nt++) {
                int nn = no + nt*16 + row16;
                float bv_ = bias[n0 + nn];
                for (int r = 0; r < 4; r++) {
                    int mm = mo + mt*16 + quad*4 + r;
                    Ts[nn*136 + mm] = __float2bfloat16(acc[mt][nt][r] + bv_);
                }
            }
        __syncthreads();
        const int b = m0 >> 11, q0b = m0 & 2047;
        for (int i = 0; i < 8; i++) {
            int chunk = t + i*256;
            int row = chunk >> 4;
            int c16 = chunk & 15;
            s16x8 val = *(const s16x8*)&Ts[row*136 + c16*8];
            *(s16x8*)(Vo + ((size_t)(b*DIM + n0 + row))*QLEN + q0b + c16*8) = val;
        }
    }
}

// ---------------- O-projection GEMM: fp32 out ----------------
__global__ __launch_bounds__(256) void gemm_out(
    const bf16* __restrict__ A, const bf16* __restrict__ B,
    const float* __restrict__ bias, float* __restrict__ out)
{
    __shared__ __align__(16) bf16 As[128*32];
    __shared__ __align__(16) bf16 Bs[128*32];

    const int t = threadIdx.x;
    const int lane = t & 63, w = t >> 6;
    const int row16 = lane & 15, quad = lane >> 4;
    const int m0 = blockIdx.y * 128, n0 = blockIdx.x * 128;
    const int mo = (w >> 1) * 64, no = (w & 1) * 64;

    f32x4 acc[4][4];
    for (int i = 0; i < 4; i++)
        for (int j = 0; j < 4; j++)
            acc[i][j] = (f32x4){0.f, 0.f, 0.f, 0.f};

    const int arow = t >> 2;
    const int achunk = (t & 3) * 8;

    for (int kt = 0; kt < DIM; kt += 32) {
        __syncthreads();
        gload_lds16(A + (size_t)(m0 + arow) * DIM + kt + achunk,      &As[arow*32 + achunk]);
        gload_lds16(A + (size_t)(m0 + 64 + arow) * DIM + kt + achunk, &As[(64+arow)*32 + achunk]);
        gload_lds16(B + (size_t)(n0 + arow) * DIM + kt + achunk,      &Bs[arow*32 + achunk]);
        gload_lds16(B + (size_t)(n0 + 64 + arow) * DIM + kt + achunk, &Bs[(64+arow)*32 + achunk]);
        __syncthreads();

        s16x8 af[4], bfr[4];
        for (int mt = 0; mt < 4; mt++)
            af[mt] = *(const s16x8*)&As[(mo + mt*16 + row16)*32 + quad*8];
        for (int nt = 0; nt < 4; nt++)
            bfr[nt] = *(const s16x8*)&Bs[(no + nt*16 + row16)*32 + quad*8];
        for (int mt = 0; mt < 4; mt++)
            for (int nt = 0; nt < 4; nt++)
                acc[mt][nt] = __builtin_amdgcn_mfma_f32_16x16x32_bf16(
                    af[mt], bfr[nt], acc[mt][nt], 0, 0, 0);
    }

    for (int mt = 0; mt < 4; mt++)
        for (int nt = 0; nt < 4; nt++) {
            int n = n0 + no + nt*16 + row16;
            float bv_ = bias[n];
            for (int r = 0; r < 4; r++) {
                int m = m0 + mo + mt*16 + quad*4 + r;
                out[(size_t)m * DIM + n] = acc[mt][nt][r] + bv_;
            }
        }
}

// ---------------- flash attention: fixed-offset softmax (no running max) ----------------
// Q pre-scaled by log2(e)/sqrt(DH); p = exp2(s - 20); offset cancels in o/l.
// K tile: Ks[r][chunk c] swizzled c = g ^ (r&15).  V tile: Vs[d][c], c = g ^ (d&7).
__global__ __launch_bounds__(256, 2) void attn(
    const bf16* __restrict__ Q, const bf16* __restrict__ Kb,
    const bf16* __restrict__ Vt, const int* __restrict__ mask,
    bf16* __restrict__ Ctx)
{
    __shared__ __align__(16) bf16 Ks[64*128];     // 16 KB
    __shared__ __align__(16) bf16 Vs[128*64];     // 16 KB
    __shared__ __align__(16) bf16 Pl[4][32*72];   // per-wave P, stride 72

    const int t = threadIdx.x, w = t >> 6, lane = t & 63;
    const int row16 = lane & 15, quad = lane >> 4;
    const int bh = blockIdx.y, b = bh >> 4, h = bh & 15;
    const int q0 = blockIdx.x * 128 + w * 32;

    s16x8 qf[2][4];
    for (int qs = 0; qs < 2; qs++) {
        const bf16* qp = Q + (size_t)(b*QLEN + q0 + qs*16 + row16) * DIM + h*DH;
        for (int ks = 0; ks < 4; ks++)
            qf[qs][ks] = *(const s16x8*)(qp + ks*32 + quad*8);
    }

    f32x4 o[2][8];
    for (int qs = 0; qs < 2; qs++)
        for (int i = 0; i < 8; i++) o[qs][i] = (f32x4){0.f, 0.f, 0.f, 0.f};
    float lsum[2][4] = {{0.f,0.f,0.f,0.f},{0.f,0.f,0.f,0.f}};
    const int* mrow = mask + b * QLEN;

    const bf16* Kbase = Kb + (size_t)b*QLEN*DIM + h*DH;
    const bf16* Vbase = Vt + ((size_t)b*DIM + h*DH) * QLEN;

    for (int kt = 0; kt < QLEN; kt += 64) {
        __syncthreads();
        #pragma unroll
        for (int i = 0; i < 4; i++) {
            int idx = (w*4 + i)*64 + lane;
            int kr = idx >> 4, kc = idx & 15;
            int kg = kc ^ (kr & 15);
            gload_lds16(Kbase + (size_t)(kt + kr) * DIM + kg*8, &Ks[idx*8]);
            int vd = idx >> 3, vc = idx & 7;
            int vg = vc ^ (vd & 7);
            gload_lds16(Vbase + (size_t)vd * QLEN + kt + vg*8, &Vs[idx*8]);
        }
        __syncthreads();

        // ---- scores: 32 q-rows x 64 k-cols ----
        f32x4 sc[2][4];
        for (int qs = 0; qs < 2; qs++)
            for (int nt = 0; nt < 4; nt++) sc[qs][nt] = (f32x4){0.f, 0.f, 0.f, 0.f};
        #pragma unroll
        for (int ks = 0; ks < 4; ks++) {
            #pragma unroll
            for (int nt = 0; nt < 4; nt++) {
                int rrow = nt*16 + row16;
                int c = (ks*4 + quad) ^ row16;
                s16x8 kf = *(const s16x8*)&Ks[rrow*128 + c*8];
                sc[0][nt] = __builtin_amdgcn_mfma_f32_16x16x32_bf16(qf[0][ks], kf, sc[0][nt], 0, 0, 0);
                sc[1][nt] = __builtin_amdgcn_mfma_f32_16x16x32_bf16(qf[1][ks], kf, sc[1][nt], 0, 0, 0);
            }
        }

        float mval[4];
        #pragma unroll
        for (int nt = 0; nt < 4; nt++)
            mval[nt] = (mrow[kt + nt*16 + row16] != 0) ? -20.0f : -1e30f;

        // ---- softmax numerator: p = exp2(s - 20), no cross-lane work ----
        #pragma unroll
        for (int qs = 0; qs < 2; qs++) {
            #pragma unroll
            for (int r = 0; r < 4; r++) {
                float ts = 0.f;
                #pragma unroll
                for (int nt = 0; nt < 4; nt++) {
                    float p = exp2f(sc[qs][nt][r] + mval[nt]);
                    ts += p;
                    Pl[w][(qs*16 + quad*4 + r)*72 + nt*16 + row16] = __float2bfloat16(p);
                }
                lsum[qs][r] += ts;
            }
        }

        // ---- PV ----
        #pragma unroll
        for (int kc = 0; kc < 2; kc++) {
            s16x8 pf0 = *(const s16x8*)&Pl[w][(0*16 + row16)*72 + kc*32 + quad*8];
            s16x8 pf1 = *(const s16x8*)&Pl[w][(1*16 + row16)*72 + kc*32 + quad*8];
            #pragma unroll
            for (int nt = 0; nt < 8; nt++) {
                int d = nt*16 + row16;
                int c = (kc*4 + quad) ^ (d & 7);
                s16x8 vf = *(const s16x8*)&Vs[d*64 + c*8];
                o[0][nt] = __builtin_amdgcn_mfma_f32_16x16x32_bf16(pf0, vf, o[0][nt], 0, 0, 0);
                o[1][nt] = __builtin_amdgcn_mfma_f32_16x16x32_bf16(pf1, vf, o[1][nt], 0, 0, 0);
            }
        }
    }

    // final cross-lane l reduction (once), then normalize and store
    for (int qs = 0; qs < 2; qs++) {
        float inv[4];
        for (int r = 0; r < 4; r++) {
            float ts = lsum[qs][r];
            ts += __shfl_xor(ts, 1);
            ts += __shfl_xor(ts, 2);
            ts += __shfl_xor(ts, 4);
            ts += __shfl_xor(ts, 8);
            inv[r] = 1.0f / ts;
        }
        for (int nt = 0; nt < 8; nt++)
            for (int r = 0; r < 4; r++) {
                float v = o[qs][nt][r] * inv[r];
                Ctx[(size_t)(b*QLEN + q0 + qs*16 + quad*4 + r) * DIM + h*DH + nt*16 + row16] =
                    __float2bfloat16(v);
            }
    }
}

extern "C" void kernel_launch(void* const* d_in, const int* in_sizes, int n_in,
                              void* d_out, int out_size, void* d_ws, size_t ws_size,
                              hipStream_t stream) {
    const float* x    = (const float*)d_in[0];
    const int*   mask = (const int*)d_in[1];
    const float* wq   = (const float*)d_in[2];
    const float* bq   = (const float*)d_in[3];
    const float* wk   = (const float*)d_in[4];
    const float* bk   = (const float*)d_in[5];
    const float* wv   = (const float*)d_in[6];
    const float* bv   = (const float*)d_in[7];
    const float* wo   = (const float*)d_in[8];
    const float* bo   = (const float*)d_in[9];

    char* ws = (char*)d_ws;
    const size_t MB = 1024 * 1024;
    bf16* Xb  = (bf16*)(ws);             // 16MB, later reused as Ctx
    bf16* Qb  = (bf16*)(ws + 16*MB);
    bf16* Kb  = (bf16*)(ws + 32*MB);
    bf16* Vtb = (bf16*)(ws + 48*MB);
    bf16* Wqb = (bf16*)(ws + 64*MB);
    bf16* Wkb = (bf16*)(ws + 72*MB);
    bf16* Wvb = (bf16*)(ws + 80*MB);
    bf16* Wob = (bf16*)(ws + 88*MB);
    bf16* Ctx = Xb;

    int n4x = (BS*QLEN*DIM) / 4;
    int n4w = (DIM*DIM) / 4;
    cast_kernel<<<dim3(n4x/256), 256, 0, stream>>>(x, Xb, n4x);
    cast_w4<<<dim3(n4w/256, 4), 256, 0, stream>>>(wq, wk, wv, wo, Wqb, Wkb, Wvb, Wob, n4w);

    const float qscale = 0.08838834764831845f * 1.4426950408889634f;  // 1/sqrt(128)*log2(e)
    gemm_qkv<<<dim3(DIM/128, MTOT/128, 3), 256, 0, stream>>>(
        Xb, Wqb, Wkb, Wvb, bq, bk, bv, Qb, Kb, Vtb, qscale);

    attn<<<dim3(QLEN/128, BS*H), 256, 0, stream>>>(Qb, Kb, Vtb, mask, Ctx);

    gemm_out<<<dim3(DIM/128, MTOT/128), 256, 0, stream>>>(Ctx, Wob, bo, (float*)d_out);
}

// Round 6
// 416.145 us; speedup vs baseline: 4.5019x; 1.0199x over previous
//
#include <hip/hip_runtime.h>
#include <hip/hip_bf16.h>

#define BS 2
#define QLEN 2048
#define DIM 2048
#define H 16
#define DH 128
#define MTOT (BS*QLEN)

typedef __hip_bfloat16 bf16;
using f32x4 = __attribute__((ext_vector_type(4))) float;
using s16x8 = __attribute__((ext_vector_type(8))) short;

__device__ inline void gload_lds16(const bf16* g, bf16* l) {
    __builtin_amdgcn_global_load_lds(
        (const __attribute__((address_space(1))) void*)g,
        (__attribute__((address_space(3))) void*)l,
        16, 0, 0);
}

// ---------------- fp32 -> bf16 cast: 6 slices in one dispatch ----------------
__global__ __launch_bounds__(256) void cast6(
    const float* __restrict__ x,
    const float* __restrict__ w0, const float* __restrict__ w1,
    const float* __restrict__ w2, const float* __restrict__ w3,
    bf16* xo, bf16* o0, bf16* o1, bf16* o2, bf16* o3, int n4)
{
    const float* in; bf16* out;
    switch (blockIdx.y) {
        case 0:  in = w0; out = o0; break;
        case 1:  in = w1; out = o1; break;
        case 2:  in = w2; out = o2; break;
        case 3:  in = w3; out = o3; break;
        case 4:  in = x;        out = xo;        break;
        default: in = x + 4*(size_t)n4; out = xo + 4*(size_t)n4; break;
    }
    int i = blockIdx.x * 256 + threadIdx.x;
    if (i < n4) {
        float4 v = ((const float4*)in)[i];
        __hip_bfloat162 p0 = __float22bfloat162_rn(make_float2(v.x, v.y));
        __hip_bfloat162 p1 = __float22bfloat162_rn(make_float2(v.z, v.w));
        ((__hip_bfloat162*)out)[2*i]   = p0;
        ((__hip_bfloat162*)out)[2*i+1] = p1;
    }
}

// ---------------- fused Q/K/V projection GEMM, BK=64, source-swizzled LDS ----------------
// C = (A * W^T + bias) * scale.  z=0: Q (scaled). z=1: K. z=2: V transposed
// out[(b*DIM + n)*QLEN + q].
// LDS rows stride 64 elem; slot g of row r holds global chunk g^(r&7)
// (swizzle applied to SOURCE address — global_load_lds dest is lane-ordered, m104/m108).
__global__ __launch_bounds__(256) void gemm_qkv(
    const bf16* __restrict__ A,
    const bf16* __restrict__ Wq, const bf16* __restrict__ Wk, const bf16* __restrict__ Wv,
    const float* __restrict__ bq, const float* __restrict__ bk, const float* __restrict__ bv,
    bf16* __restrict__ Qo, bf16* __restrict__ Ko, bf16* __restrict__ Vo,
    float qscale)
{
    __shared__ __align__(16) bf16 smem[128*136];   // As[128*64] @0, Bs @8192; Ts overlay
    bf16* As = smem;
    bf16* Bs = smem + 128*64;

    const int z = blockIdx.z;
    const bf16*  B    = (z == 0) ? Wq : (z == 1) ? Wk : Wv;
    const float* bias = (z == 0) ? bq : (z == 1) ? bk : bv;
    const float  scale = (z == 0) ? qscale : 1.0f;

    const int t = threadIdx.x;
    const int lane = t & 63, w = t >> 6;
    const int row16 = lane & 15, quad = lane >> 4;
    const int m0 = blockIdx.y * 128, n0 = blockIdx.x * 128;
    const int mo = (w >> 1) * 64, no = (w & 1) * 64;

    f32x4 acc[4][4];
    for (int i = 0; i < 4; i++)
        for (int j = 0; j < 4; j++)
            acc[i][j] = (f32x4){0.f, 0.f, 0.f, 0.f};

    for (int kt = 0; kt < DIM; kt += 64) {
        __syncthreads();
        #pragma unroll
        for (int i = 0; i < 4; i++) {
            int idx = i*256 + t;              // 0..1023; LDS dest = base + lane*16
            int row = idx >> 3, g = idx & 7;
            int src = g ^ (row & 7);          // source-side XOR swizzle
            gload_lds16(A + (size_t)(m0 + row) * DIM + kt + src*8, &As[idx*8]);
            gload_lds16(B + (size_t)(n0 + row) * DIM + kt + src*8, &Bs[idx*8]);
        }
        __syncthreads();

        #pragma unroll
        for (int kh = 0; kh < 2; kh++) {
            s16x8 af[4], bfr[4];
            #pragma unroll
            for (int mt = 0; mt < 4; mt++)
                af[mt] = *(const s16x8*)&As[(mo + mt*16 + row16)*64 + (((kh*4+quad) ^ (row16&7)))*8];
            #pragma unroll
            for (int nt = 0; nt < 4; nt++)
                bfr[nt] = *(const s16x8*)&Bs[(no + nt*16 + row16)*64 + (((kh*4+quad) ^ (row16&7)))*8];
            #pragma unroll
            for (int mt = 0; mt < 4; mt++)
                #pragma unroll
                for (int nt = 0; nt < 4; nt++)
                    acc[mt][nt] = __builtin_amdgcn_mfma_f32_16x16x32_bf16(
                        af[mt], bfr[nt], acc[mt][nt], 0, 0, 0);
        }
    }

    if (z < 2) {
        bf16* out = (z == 0) ? Qo : Ko;
        for (int mt = 0; mt < 4; mt++)
            for (int nt = 0; nt < 4; nt++) {
                int n = n0 + no + nt*16 + row16;
                float bv_ = bias[n];
                for (int r = 0; r < 4; r++) {
                    int m = m0 + mo + mt*16 + quad*4 + r;
                    out[(size_t)m * DIM + n] = __float2bfloat16((acc[mt][nt][r] + bv_) * scale);
                }
            }
    } else {
        __syncthreads();                 // As/Bs dead for ALL waves before Ts reuse
        bf16* Ts = smem;                 // 128*136
        for (int mt = 0; mt < 4; mt++)
            for (int nt = 0; nt < 4; nt++) {
                int nn = no + nt*16 + row16;
                float bv_ = bias[n0 + nn];
                for (int r = 0; r < 4; r++) {
                    int mm = mo + mt*16 + quad*4 + r;
                    Ts[nn*136 + mm] = __float2bfloat16(acc[mt][nt][r] + bv_);
                }
            }
        __syncthreads();
        const int b = m0 >> 11, q0b = m0 & 2047;
        for (int i = 0; i < 8; i++) {
            int chunk = t + i*256;
            int row = chunk >> 4;
            int c16 = chunk & 15;
            s16x8 val = *(const s16x8*)&Ts[row*136 + c16*8];
            *(s16x8*)(Vo + ((size_t)(b*DIM + n0 + row))*QLEN + q0b + c16*8) = val;
        }
    }
}

// ---------------- O-projection GEMM: BK=64, source-swizzled, fp32 out ----------------
__global__ __launch_bounds__(256) void gemm_out(
    const bf16* __restrict__ A, const bf16* __restrict__ B,
    const float* __restrict__ bias, float* __restrict__ out)
{
    __shared__ __align__(16) bf16 As[128*64];
    __shared__ __align__(16) bf16 Bs[128*64];

    const int t = threadIdx.x;
    const int lane = t & 63, w = t >> 6;
    const int row16 = lane & 15, quad = lane >> 4;
    const int m0 = blockIdx.y * 128, n0 = blockIdx.x * 128;
    const int mo = (w >> 1) * 64, no = (w & 1) * 64;

    f32x4 acc[4][4];
    for (int i = 0; i < 4; i++)
        for (int j = 0; j < 4; j++)
            acc[i][j] = (f32x4){0.f, 0.f, 0.f, 0.f};

    for (int kt = 0; kt < DIM; kt += 64) {
        __syncthreads();
        #pragma unroll
        for (int i = 0; i < 4; i++) {
            int idx = i*256 + t;
            int row = idx >> 3, g = idx & 7;
            int src = g ^ (row & 7);
            gload_lds16(A + (size_t)(m0 + row) * DIM + kt + src*8, &As[idx*8]);
            gload_lds16(B + (size_t)(n0 + row) * DIM + kt + src*8, &Bs[idx*8]);
        }
        __syncthreads();

        #pragma unroll
        for (int kh = 0; kh < 2; kh++) {
            s16x8 af[4], bfr[4];
            #pragma unroll
            for (int mt = 0; mt < 4; mt++)
                af[mt] = *(const s16x8*)&As[(mo + mt*16 + row16)*64 + (((kh*4+quad) ^ (row16&7)))*8];
            #pragma unroll
            for (int nt = 0; nt < 4; nt++)
                bfr[nt] = *(const s16x8*)&Bs[(no + nt*16 + row16)*64 + (((kh*4+quad) ^ (row16&7)))*8];
            #pragma unroll
            for (int mt = 0; mt < 4; mt++)
                #pragma unroll
                for (int nt = 0; nt < 4; nt++)
                    acc[mt][nt] = __builtin_amdgcn_mfma_f32_16x16x32_bf16(
                        af[mt], bfr[nt], acc[mt][nt], 0, 0, 0);
        }
    }

    for (int mt = 0; mt < 4; mt++)
        for (int nt = 0; nt < 4; nt++) {
            int n = n0 + no + nt*16 + row16;
            float bv_ = bias[n];
            for (int r = 0; r < 4; r++) {
                int m = m0 + mo + mt*16 + quad*4 + r;
                out[(size_t)m * DIM + n] = acc[mt][nt][r] + bv_;
            }
        }
}

// ---------------- flash attention: dbuf-K, covered-latency staging ----------------
// Q pre-scaled by log2(e)/sqrt(DH); p = exp2(s - 20); offset cancels in o/l.
// Ks[buf]: 64 rows x 16 chunks, slot c holds global chunk c^(row&15) (source swizzle).
// Vs: 128 d-rows x 8 chunks, slot c holds chunk c^(d&7) (source swizzle).
// Pl: per-wave 32 rows x 8 chunks (stride 64), chunk g at slot g^(row&7) (ds_write).
__global__ __launch_bounds__(256, 2) void attn(
    const bf16* __restrict__ Q, const bf16* __restrict__ Kb,
    const bf16* __restrict__ Vt, const int* __restrict__ mask,
    bf16* __restrict__ Ctx)
{
    __shared__ __align__(16) bf16 Ks[2][64*128];  // 32 KB
    __shared__ __align__(16) bf16 Vs[128*64];     // 16 KB
    __shared__ __align__(16) bf16 Pl[4][32*64];   // 16 KB (swizzled, no pad)

    const int t = threadIdx.x, w = t >> 6, lane = t & 63;
    const int row16 = lane & 15, quad = lane >> 4;
    const int bh = blockIdx.y, b = bh >> 4, h = bh & 15;
    const int q0 = blockIdx.x * 128 + w * 32;

    s16x8 qf[2][4];
    for (int qs = 0; qs < 2; qs++) {
        const bf16* qp = Q + (size_t)(b*QLEN + q0 + qs*16 + row16) * DIM + h*DH;
        for (int ks = 0; ks < 4; ks++)
            qf[qs][ks] = *(const s16x8*)(qp + ks*32 + quad*8);
    }

    f32x4 o[2][8];
    for (int qs = 0; qs < 2; qs++)
        for (int i = 0; i < 8; i++) o[qs][i] = (f32x4){0.f, 0.f, 0.f, 0.f};
    float lsum[2][4] = {{0.f,0.f,0.f,0.f},{0.f,0.f,0.f,0.f}};
    const int* mrow = mask + b * QLEN;

    const bf16* Kbase = Kb + (size_t)b*QLEN*DIM + h*DH;
    const bf16* Vbase = Vt + ((size_t)b*DIM + h*DH) * QLEN;

    // prologue: K tile 0 into buf 0
    #pragma unroll
    for (int i = 0; i < 4; i++) {
        int idx = i*256 + t;
        int kr = idx >> 4, kc = idx & 15;
        int kg = kc ^ (kr & 15);
        gload_lds16(Kbase + (size_t)kr * DIM + kg*8, &Ks[0][idx*8]);
    }

    for (int it = 0; it < QLEN/64; it++) {
        const int kt = it * 64, buf = it & 1;
        __syncthreads();   // drains K(it) [+V(it-1)]; all waves done PV(it-1)

        // prefetch K(it+1) and V(it): land during compute below
        if (it + 1 < QLEN/64) {
            #pragma unroll
            for (int i = 0; i < 4; i++) {
                int idx = i*256 + t;
                int kr = idx >> 4, kc = idx & 15;
                int kg = kc ^ (kr & 15);
                gload_lds16(Kbase + (size_t)(kt + 64 + kr) * DIM + kg*8, &Ks[buf^1][idx*8]);
            }
        }
        #pragma unroll
        for (int i = 0; i < 4; i++) {
            int idx = i*256 + t;
            int vd = idx >> 3, vc = idx & 7;
            int vg = vc ^ (vd & 7);
            gload_lds16(Vbase + (size_t)vd * QLEN + kt + vg*8, &Vs[idx*8]);
        }

        float mval[4];
        #pragma unroll
        for (int nt = 0; nt < 4; nt++)
            mval[nt] = (mrow[kt + nt*16 + row16] != 0) ? -20.0f : -1e30f;

        // ---- scores from Ks[buf] ----
        f32x4 sc[2][4];
        for (int qs = 0; qs < 2; qs++)
            for (int nt = 0; nt < 4; nt++) sc[qs][nt] = (f32x4){0.f, 0.f, 0.f, 0.f};
        #pragma unroll
        for (int ks = 0; ks < 4; ks++) {
            #pragma unroll
            for (int nt = 0; nt < 4; nt++) {
                int rrow = nt*16 + row16;
                int c = (ks*4 + quad) ^ row16;
                s16x8 kf = *(const s16x8*)&Ks[buf][rrow*128 + c*8];
                sc[0][nt] = __builtin_amdgcn_mfma_f32_16x16x32_bf16(qf[0][ks], kf, sc[0][nt], 0, 0, 0);
                sc[1][nt] = __builtin_amdgcn_mfma_f32_16x16x32_bf16(qf[1][ks], kf, sc[1][nt], 0, 0, 0);
            }
        }

        // ---- softmax numerator: p = exp2(s - 20) -> Pl (swizzled via ds_write) ----
        #pragma unroll
        for (int qs = 0; qs < 2; qs++) {
            #pragma unroll
            for (int r = 0; r < 4; r++) {
                int prow = qs*16 + quad*4 + r;
                float ts = 0.f;
                #pragma unroll
                for (int nt = 0; nt < 4; nt++) {
                    float p = exp2f(sc[qs][nt][r] + mval[nt]);
                    ts += p;
                    int chunk = nt*2 + (row16 >> 3);
                    int slot = chunk ^ (prow & 7);
                    Pl[w][prow*64 + slot*8 + (row16 & 7)] = __float2bfloat16(p);
                }
                lsum[qs][r] += ts;
            }
        }

        __syncthreads();   // drains V(it) [+K(it+1)], both covered by QK+softmax

        // ---- PV from Vs ----
        #pragma unroll
        for (int kc = 0; kc < 2; kc++) {
            int pslot0 = ((kc*4 + quad) ^ (row16 & 7));
            s16x8 pf0 = *(const s16x8*)&Pl[w][(0*16 + row16)*64 + pslot0*8];
            s16x8 pf1 = *(const s16x8*)&Pl[w][(1*16 + row16)*64 + pslot0*8];
            #pragma unroll
            for (int nt = 0; nt < 8; nt++) {
                int d = nt*16 + row16;
                int c = (kc*4 + quad) ^ (d & 7);
                s16x8 vf = *(const s16x8*)&Vs[d*64 + c*8];
                o[0][nt] = __builtin_amdgcn_mfma_f32_16x16x32_bf16(pf0, vf, o[0][nt], 0, 0, 0);
                o[1][nt] = __builtin_amdgcn_mfma_f32_16x16x32_bf16(pf1, vf, o[1][nt], 0, 0, 0);
            }
        }
    }

    for (int qs = 0; qs < 2; qs++) {
        float inv[4];
        for (int r = 0; r < 4; r++) {
            float ts = lsum[qs][r];
            ts += __shfl_xor(ts, 1);
            ts += __shfl_xor(ts, 2);
            ts += __shfl_xor(ts, 4);
            ts += __shfl_xor(ts, 8);
            inv[r] = 1.0f / ts;
        }
        for (int nt = 0; nt < 8; nt++)
            for (int r = 0; r < 4; r++) {
                float v = o[qs][nt][r] * inv[r];
                Ctx[(size_t)(b*QLEN + q0 + qs*16 + quad*4 + r) * DIM + h*DH + nt*16 + row16] =
                    __float2bfloat16(v);
            }
    }
}

extern "C" void kernel_launch(void* const* d_in, const int* in_sizes, int n_in,
                              void* d_out, int out_size, void* d_ws, size_t ws_size,
                              hipStream_t stream) {
    const float* x    = (const float*)d_in[0];
    const int*   mask = (const int*)d_in[1];
    const float* wq   = (const float*)d_in[2];
    const float* bq   = (const float*)d_in[3];
    const float* wk   = (const float*)d_in[4];
    const float* bk   = (const float*)d_in[5];
    const float* wv   = (const float*)d_in[6];
    const float* bv   = (const float*)d_in[7];
    const float* wo   = (const float*)d_in[8];
    const float* bo   = (const float*)d_in[9];

    char* ws = (char*)d_ws;
    const size_t MB = 1024 * 1024;
    bf16* Xb  = (bf16*)(ws);             // 16MB, later reused as Ctx
    bf16* Qb  = (bf16*)(ws + 16*MB);
    bf16* Kb  = (bf16*)(ws + 32*MB);
    bf16* Vtb = (bf16*)(ws + 48*MB);
    bf16* Wqb = (bf16*)(ws + 64*MB);
    bf16* Wkb = (bf16*)(ws + 72*MB);
    bf16* Wvb = (bf16*)(ws + 80*MB);
    bf16* Wob = (bf16*)(ws + 88*MB);
    bf16* Ctx = Xb;

    int n4w = (DIM*DIM) / 4;             // 1,048,576 float4s per weight / per x-half
    cast6<<<dim3(n4w/256, 6), 256, 0, stream>>>(x, wq, wk, wv, wo,
                                                Xb, Wqb, Wkb, Wvb, Wob, n4w);

    const float qscale = 0.08838834764831845f * 1.4426950408889634f;  // 1/sqrt(128)*log2(e)
    gemm_qkv<<<dim3(DIM/128, MTOT/128, 3), 256, 0, stream>>>(
        Xb, Wqb, Wkb, Wvb, bq, bk, bv, Qb, Kb, Vtb, qscale);

    attn<<<dim3(QLEN/128, BS*H), 256, 0, stream>>>(Qb, Kb, Vtb, mask, Ctx);

    gemm_out<<<dim3(DIM/128, MTOT/128), 256, 0, stream>>>(Ctx, Wob, bo, (float*)d_out);
}